// Round 1
// baseline (136.089 us; speedup 1.0000x reference)
//
#include <hip/hip_runtime.h>

// Each (B,S) element = 32 floats (exact 0.0/1.0).
//   exp bits  : idx 1..8  (idx1 = MSB)
//   mant bits : idx 9..12 (m0..m3)
// shift = (eint + 129) & 255  (== eint - 127 mod 256)
// if shift <= 4: val5 = (16 | m0<<3|m1<<2|m2<<1|m3) >> (4 - shift), else 0
// out[j] (j=0..4) = bit (4-j) of val5, as float 0.0/1.0.

#define BIT(u) (((u) >> 23) & 1u)

__global__ __launch_bounds__(256) void spike_kernel(
    const uint4* __restrict__ in, uint4* __restrict__ out, int n4)
{
    int tid = blockIdx.x * blockDim.x + threadIdx.x;
    if (tid >= n4) return;

    // 4 elements per thread; each element = 8 uint4 (128B); we read only the
    // first 4 uint4 (indices 0..15 -> we need 1..12).
    const uint4* p = in + (size_t)tid * 32;

    unsigned int vals[4];
#pragma unroll
    for (int k = 0; k < 4; ++k) {
        uint4 a = p[k * 8 + 0];   // idx 0..3
        uint4 b = p[k * 8 + 1];   // idx 4..7
        uint4 c = p[k * 8 + 2];   // idx 8..11
        uint4 d = p[k * 8 + 3];   // idx 12..15

        unsigned int eint =
            (BIT(a.y) << 7) | (BIT(a.z) << 6) | (BIT(a.w) << 5) |
            (BIT(b.x) << 4) | (BIT(b.y) << 3) | (BIT(b.z) << 2) |
            (BIT(b.w) << 1) |  BIT(c.x);
        unsigned int shift = (eint + 129u) & 255u;
        unsigned int mb = 16u |
            (BIT(c.y) << 3) | (BIT(c.z) << 2) | (BIT(c.w) << 1) | BIT(d.x);
        vals[k] = (shift <= 4u) ? (mb >> (4u - shift)) : 0u;
    }

    // 4 elements * 5 outputs = 20 floats = 5 uint4 (byte offset tid*80, 16B aligned)
    unsigned int bits[20];
#pragma unroll
    for (int k = 0; k < 4; ++k) {
#pragma unroll
        for (int j = 0; j < 5; ++j) {
            unsigned int b1 = (vals[k] >> (4 - j)) & 1u;
            bits[k * 5 + j] = (0u - b1) & 0x3f800000u;  // 1 -> 1.0f, 0 -> 0.0f
        }
    }

    uint4* q = out + (size_t)tid * 5;
#pragma unroll
    for (int v = 0; v < 5; ++v)
        q[v] = make_uint4(bits[v * 4 + 0], bits[v * 4 + 1],
                          bits[v * 4 + 2], bits[v * 4 + 3]);
}

extern "C" void kernel_launch(void* const* d_in, const int* in_sizes, int n_in,
                              void* d_out, int out_size, void* d_ws, size_t ws_size,
                              hipStream_t stream) {
    (void)n_in; (void)d_ws; (void)ws_size; (void)out_size;
    const uint4* in = (const uint4*)d_in[0];
    uint4* out = (uint4*)d_out;

    int n_elem = in_sizes[0] / 32;   // 4,194,304
    int n4 = n_elem / 4;             // 1,048,576 threads (divisible)

    const int block = 256;
    int grid = (n4 + block - 1) / block;
    spike_kernel<<<grid, block, 0, stream>>>(in, out, n4);
}

// Round 2
// 124.782 us; speedup vs baseline: 1.0906x; 1.0906x over previous
//
#include <hip/hip_runtime.h>

// Each (B,S) element = 32 floats (exact 0.0/1.0), 128 B. Needed bits live in
// dwords 1..12 -> first 64 B sector only.
//   eint  = idx1..8 (MSB-first), mant = idx9..12
//   shift = (eint + 129) & 255; val5 = shift<=4 ? (16|mant) >> (4-shift) : 0
//   out dword j (j=0..4) = bit (4-j) of val5 as float 0.0/1.0
//
// Coalescing scheme: 4 lanes per element (lane sub = t&3 loads uint4 #sub of
// the element's first 64 B -> contiguous 64 B segments per instruction).
// Bits combined across the quad with 2 DPP quad_perm OR-butterflies.
// Output staged in LDS, then written as fully coalesced uint4 stores.

#define BIT(u) (((u) >> 23) & 1u)

__global__ __launch_bounds__(256) void spike_kernel(
    const uint4* __restrict__ in, uint4* __restrict__ out)
{
    __shared__ unsigned int obuf[5120];  // 1024 elements * 5 dwords = 20 KiB

    const int t   = threadIdx.x;
    const int sub = t & 3;     // which 16B chunk of the element's first 64B
    const int egq = t >> 2;    // element slot 0..63 within an iteration
    const size_t blk_e0 = (size_t)blockIdx.x * 1024;

    const int nib_shift     = (3 - sub) * 4;  // nibble position in 16-bit word
    const int out_bit_shift = 4 - sub;        // val5 bit for output dword `sub`

#pragma unroll
    for (int i = 0; i < 16; ++i) {
        const int e_local = i * 64 + egq;
        uint4 u = in[(blk_e0 + e_local) * 8 + sub];

        unsigned int nib = (BIT(u.x) << 3) | (BIT(u.y) << 2) |
                           (BIT(u.z) << 1) |  BIT(u.w);
        int V = (int)(nib << nib_shift);
        V |= __builtin_amdgcn_mov_dpp(V, 0xB1, 0xF, 0xF, true); // quad_perm [1,0,3,2]
        V |= __builtin_amdgcn_mov_dpp(V, 0x4E, 0xF, 0xF, true); // quad_perm [2,3,0,1]
        unsigned int Vu = (unsigned int)V;
        // Vu: bit15=idx0 ... bit0=idx15
        unsigned int eint  = (Vu >> 7) & 0xFFu;  // idx1..8
        unsigned int mant  = (Vu >> 3) & 0xFu;   // idx9..12
        unsigned int shift = (eint + 129u) & 255u;
        unsigned int mb    = 16u | mant;
        unsigned int val5  = (shift <= 4u) ? (mb >> (4u - shift)) : 0u;

        unsigned int* ob = &obuf[e_local * 5];
        ob[sub] = (0u - ((val5 >> out_bit_shift) & 1u)) & 0x3f800000u;
        if (sub == 0)
            ob[4] = (0u - (val5 & 1u)) & 0x3f800000u;
    }

    __syncthreads();

    const uint4* ob4 = (const uint4*)obuf;
    uint4* q = out + (size_t)blockIdx.x * 1280;
#pragma unroll
    for (int k = 0; k < 5; ++k)
        q[k * 256 + t] = ob4[k * 256 + t];
}

extern "C" void kernel_launch(void* const* d_in, const int* in_sizes, int n_in,
                              void* d_out, int out_size, void* d_ws, size_t ws_size,
                              hipStream_t stream) {
    (void)n_in; (void)d_ws; (void)ws_size; (void)out_size;
    const uint4* in = (const uint4*)d_in[0];
    uint4* out = (uint4*)d_out;

    int n_elem = in_sizes[0] / 32;          // 4,194,304
    int grid   = n_elem / 1024;             // 4096 blocks, 1024 elem each
    spike_kernel<<<grid, 256, 0, stream>>>(in, out);
}